// Round 17
// baseline (63.755 us; speedup 1.0000x reference)
//
#include <hip/hip_runtime.h>

#define B_ 16
#define T_ 400
#define NH_ 100
#define NB_ 65
#define BLK_ 160
#define SR_ 16000
#define N_ 64000           // T_*BLK_
#define REV_ 16000
#define KPAD_ 16128        // front zero pad of signal
#define KTOT_ 80128        // KPAD_ + N_
#define KTOT2_ 80160       // + 32-sample zero tail (dual-window B reads)
#define NWG_ 250           // 256 outputs per block
#define ISTRIDE_ 16768     // elems per IMPREV copy

typedef __attribute__((ext_vector_type(8))) _Float16 f16x8;
typedef __attribute__((ext_vector_type(2))) _Float16 f16x2;
typedef __attribute__((ext_vector_type(4))) float f32x4;
typedef __attribute__((ext_vector_type(16))) float f32x16;
typedef __attribute__((ext_vector_type(4))) unsigned uint4v;
typedef uint4v __attribute__((aligned(4))) uint4v_a4;

static __device__ __forceinline__ float dot2f(f16x2 a, f16x2 b, float c) {
#if __has_builtin(__builtin_amdgcn_fdot2)
  return __builtin_amdgcn_fdot2(a, b, c, false);
#else
  return fmaf((float)a[0], (float)b[0], fmaf((float)a[1], (float)b[1], c));
#endif
}

// ---------------- K0: IMPREV build (66) + PH pad zero front+tail (64) + fp64 prefix (16) ----------------
// IMPREV[c][u] = imp[16383 - u - c] (0 outside [0,REV_)), imp[0]=1.
__global__ __launch_bounds__(512) void k_pre(const float* __restrict__ pitch,
                                             const float* __restrict__ rn,
                                             const float* __restrict__ dec,
                                             const float* __restrict__ wet,
                                             double* __restrict__ Pv,
                                             double* __restrict__ Xv,
                                             _Float16* __restrict__ IMPREV,
                                             _Float16* __restrict__ PH) {
  const int blk = blockIdx.x, tid = threadIdx.x;
  if (blk < 66) {
    const int gid = blk * 512 + tid;
    if (gid < 2 * ISTRIDE_) {
      const int c = gid / ISTRIDE_, u = gid - c * ISTRIDE_;
      const int i = 16383 - u - c;
      float v = 0.f;
      if (i == 0) {
        v = 1.0f;
      } else if (i > 0 && i < REV_) {
        const float a = log1pf(expf(-dec[0]));
        const float sg = 1.f / (1.f + expf(-wet[0]));
        v = rn[i] * expf(-a * ((float)i / (float)SR_) * 500.0f) * sg;
      }
      IMPREV[gid] = (_Float16)v;
    }
    return;
  }
  if (blk < 130) {
    const int gid = (blk - 66) * 512 + tid;   // < 32768
    if (gid < 32256) {
      ((f32x4*)PH)[gid] = (f32x4){0.f, 0.f, 0.f, 0.f};                 // front pad
    } else if (gid < 32320) {
      ((f32x4*)PH)[160256 + gid - 32256] = (f32x4){0.f, 0.f, 0.f, 0.f}; // tail pad
    }
    return;
  }
  // ---- prefix branch ----
  __shared__ double s[512];
  const int b = blk - 130, t = tid;
  double x = 0.0;
  if (t < T_) x = (double)pitch[b * T_ + t] * (1.0 / (double)SR_);
  s[t] = x;
  __syncthreads();
  for (int off = 1; off < 512; off <<= 1) {
    double v = (t >= off) ? s[t - off] : 0.0;
    __syncthreads();
    s[t] += v;
    __syncthreads();
  }
  if (t < T_) {
    Xv[b * T_ + t] = x;
    Pv[b * T_ + t] = (s[t] - x) * 160.0;
  }
}

// ---------------- K2: dual-column harmonic synth + filtered noise -> packed fp16 (r13-identical) ----------------
__global__ __launch_bounds__(320) void k_synth(
    const float* __restrict__ pitch, const float* __restrict__ tamp,
    const float* __restrict__ harmo, const float* __restrict__ nfilt,
    const float* __restrict__ noise, const double* __restrict__ Pv,
    const double* __restrict__ Xv, _Float16* __restrict__ PH) {
  const int tid = threadIdx.x;
  const int g = (tid >= 160) ? 1 : 0;
  const int ltid = tid - (g << 7) - (g << 5);  // tid - 160*g
  const int bt = (blockIdx.x << 1) + g;
  const int b = bt / T_, t = bt - b * T_;
  __shared__ __align__(16) float amp[2][112];
  __shared__ __align__(16) float a_s[2][68];
  __shared__ __align__(16) float ir_s[2][68];
  __shared__ __align__(16) _Float16 C0[2][320];
  __shared__ __align__(16) _Float16 C1[2][320];
  __shared__ __align__(16) _Float16 imp_sw[2][128];
  __shared__ float red_s[2];

  const float pv = pitch[bt];
  int nv = (int)(8000.0f / pv);
  if (nv > NH_) nv = NH_;
  while (nv < NH_ && (float)(nv + 1) * pv < 8000.0f) ++nv;
  while (nv > 0 && (float)nv * pv >= 8000.0f) --nv;

  if (ltid < NB_) a_s[g][ltid] = nfilt[bt * NB_ + ltid];
  {
    const _Float16 nh = (_Float16)noise[bt * BLK_ + ltid];
    C0[g][160 + ltid] = nh;
    C1[g][159 + ltid] = nh;
    C0[g][ltid] = (_Float16)0.f;
    if (ltid < 159) C1[g][ltid] = (_Float16)0.f;
  }
  if (ltid < NH_) {
    const float ha = harmo[(b * NH_ + ltid) * T_ + t];
    const float aa = (pv * (float)(ltid + 1) < 8000.0f ? 1.0f : 0.0f) + 1e-4f;
    amp[g][ltid] = ha * aa;
  } else if (ltid < 112) {
    amp[g][ltid] = 0.f;
  }
  __syncthreads();  // B1

  float irv = 0.f;
  if (ltid < 65) {
    const float phi = (float)ltid * (1.0f / 128.0f);
    const float c1 = __builtin_amdgcn_cosf(phi);
    const float c2 = fmaf(2.f * c1, c1, -1.f);
    const float c3 = fmaf(2.f * c2, c1, -c1);
    const float c4 = fmaf(2.f * c2, c2, -1.f);
    const float tc = 2.f * c4;
    float x0 = 1.f, p0 = c4;
    float x1 = c1, p1 = c3;
    float x2 = c2, p2 = c2;
    float x3 = c3, p3 = c1;
    float a0 = 0.f, a1 = 0.f, a2 = 0.f, a3 = 0.f;
#pragma unroll
    for (int m = 0; m < 8; ++m) {
      const f32x4 aA = *(const f32x4*)&a_s[g][m << 3];
      const f32x4 aB = *(const f32x4*)&a_s[g][(m << 3) + 4];
      a0 = fmaf(aA[0], x0, a0); const float y0 = fmaf(tc, x0, -p0);
      a1 = fmaf(aA[1], x1, a1); const float y1 = fmaf(tc, x1, -p1);
      a2 = fmaf(aA[2], x2, a2); const float y2 = fmaf(tc, x2, -p2);
      a3 = fmaf(aA[3], x3, a3); const float y3 = fmaf(tc, x3, -p3);
      a0 = fmaf(aB[0], y0, a0); const float z0 = fmaf(tc, y0, -x0); p0 = y0; x0 = z0;
      a1 = fmaf(aB[1], y1, a1); const float z1 = fmaf(tc, y1, -x1); p1 = y1; x1 = z1;
      a2 = fmaf(aB[2], y2, a2); const float z2 = fmaf(tc, y2, -x2); p2 = y2; x2 = z2;
      a3 = fmaf(aB[3], y3, a3); const float z3 = fmaf(tc, y3, -x3); p3 = y3; x3 = z3;
    }
    const float accS = (a0 + a1) + (a2 + a3);
    irv = (2.f * accS - a_s[g][0] + ((ltid & 1) ? -a_s[g][64] : a_s[g][64])) * (1.0f / 128.0f);
    ir_s[g][ltid] = irv;
  } else if (ltid >= 128) {
    const int l = ltid - 128;
    float v = amp[g][l] + amp[g][l + 32] + amp[g][l + 64] + (l < 4 ? amp[g][l + 96] : 0.f);
    v += __shfl_xor(v, 16);
    v += __shfl_xor(v, 8);
    v += __shfl_xor(v, 4);
    v += __shfl_xor(v, 2);
    v += __shfl_xor(v, 1);
    if (l == 0) red_s[g] = v;
  }
  __syncthreads();  // B2

  if (ltid < 64) {
    const float w = 0.5f + 0.5f * __builtin_amdgcn_cosf((float)ltid * (1.0f / 128.0f));
    imp_sw[g][ltid ^ 1] = (_Float16)(w * irv);
  } else if (ltid >= 96 && ltid < 160) {
    const int u = ltid - 96;
    const float w = 0.5f - 0.5f * __builtin_amdgcn_cosf((float)u * (1.0f / 128.0f));
    imp_sw[g][64 + (u ^ 1)] = (_Float16)(w * ir_s[g][64 - u]);
  }
  const float scale = tamp[bt] / red_s[g];
  double th = Pv[bt] + (double)(ltid + 1) * Xv[bt];
  th -= floor(th);
  const float theta = (float)th;
  const float cT = __builtin_amdgcn_cosf(theta);
  const float sT = __builtin_amdgcn_sinf(theta);
  __syncthreads();  // B3

  float acc;
  {
    const float c2 = fmaf(cT, cT, -sT * sT);
    const float s2 = 2.f * cT * sT;
    const float s3 = fmaf(s2, cT, c2 * sT);
    const float s4 = 2.f * s2 * c2;
    const float c4 = fmaf(2.f * c2, c2, -1.f);
    const float tc = 2.f * c4;
    float x0 = sT, p0 = -s3;
    float x1 = s2, p1 = -s2;
    float x2 = s3, p2 = -sT;
    float x3 = s4, p3 = 0.f;
    float a0 = 0.f, a1 = 0.f, a2 = 0.f, a3 = 0.f;
    const int S = (nv + 7) >> 3;
    for (int m = 0; m < S; ++m) {
      const f32x4 aA = *(const f32x4*)&amp[g][m << 3];
      const f32x4 aB = *(const f32x4*)&amp[g][(m << 3) + 4];
      a0 = fmaf(aA[0], x0, a0); const float y0 = fmaf(tc, x0, -p0);
      a1 = fmaf(aA[1], x1, a1); const float y1 = fmaf(tc, x1, -p1);
      a2 = fmaf(aA[2], x2, a2); const float y2 = fmaf(tc, x2, -p2);
      a3 = fmaf(aA[3], x3, a3); const float y3 = fmaf(tc, x3, -p3);
      a0 = fmaf(aB[0], y0, a0); const float z0 = fmaf(tc, y0, -x0); p0 = y0; x0 = z0;
      a1 = fmaf(aB[1], y1, a1); const float z1 = fmaf(tc, y1, -x1); p1 = y1; x1 = z1;
      a2 = fmaf(aB[2], y2, a2); const float z2 = fmaf(tc, y2, -x2); p2 = y2; x2 = z2;
      a3 = fmaf(aB[3], y3, a3); const float z3 = fmaf(tc, y3, -x3); p3 = y3; x3 = z3;
    }
    acc = ((a0 + a1) + (a2 + a3)) * scale;
  }

  float nf = 0.f;
  {
    const f16x2* np0;
    int pe;
    if (ltid & 1) {
      np0 = (const f16x2*)C0[g];
      pe = (159 + ltid) >> 1;
    } else {
      np0 = (const f16x2*)C1[g];
      pe = (158 + ltid) >> 1;
    }
    const f16x8* ip = (const f16x8*)imp_sw[g];
#pragma unroll
    for (int k0 = 0; k0 < 8; ++k0) {
      const f16x8 i8 = ip[k0];
      const int kb = k0 << 2;
      nf = dot2f((f16x2){i8[0], i8[1]}, np0[pe - kb], nf);
      nf = dot2f((f16x2){i8[2], i8[3]}, np0[pe - kb - 1], nf);
      nf = dot2f((f16x2){i8[4], i8[5]}, np0[pe - kb - 2], nf);
      nf = dot2f((f16x2){i8[6], i8[7]}, np0[pe - kb - 3], nf);
    }
#pragma unroll
    for (int k0 = 0; k0 < 8; ++k0) {
      const f16x8 i8 = ip[8 + k0];
      const int kb = (k0 << 2) + 48;
      nf = dot2f((f16x2){i8[0], i8[1]}, np0[pe - kb], nf);
      nf = dot2f((f16x2){i8[2], i8[3]}, np0[pe - kb - 1], nf);
      nf = dot2f((f16x2){i8[4], i8[5]}, np0[pe - kb - 2], nf);
      nf = dot2f((f16x2){i8[6], i8[7]}, np0[pe - kb - 3], nf);
    }
  }

  const float v = acc + nf;
  const unsigned k = (unsigned)(KPAD_ + t * BLK_ + ltid);
  const unsigned off = ((k >> 3) << 7) + ((unsigned)b << 3) + (k & 7u);
  PH[off] = (_Float16)v;
}

// ---------------- K4: reverb Toeplitz GEMM via mfma_f32_32x32x16_f16, dual-window columns ----------------
static __device__ __forceinline__ f32x16 mfma32(f16x8 a, f16x8 b, f32x16 c) {
  return __builtin_amdgcn_mfma_f32_32x32x16_f16(a, b, c, 0, 0, 0);
}

static __device__ __forceinline__ f16x8 lfrag(const unsigned short* __restrict__ base, int byteoff) {
  union { uint4v u; f16x8 v; } x;
  x.u = *(const uint4v_a4*)((const char*)base + byteoff);  // single dwordx4, 4B-aligned
  return x.v;
}

// step s (U = s mod 16): 4 MFMAs (q=0..3 use ring slots (U-4q)&15), shared B;
// ISSUE loads frag(0,s+4)/B(s+4) into buf[U&3]; CONSUME installs step s+1 data.
template <int U, bool ISSUE, bool CONSUME>
__device__ __forceinline__ void cstep(f16x8 (&Rng)[16], f32x16 (&acc)[4], f16x8& bhi,
                                      f16x8 (&na)[4], f16x8 (&nbB)[4],
                                      const f16x8* __restrict__ phB,
                                      const unsigned short* __restrict__ abase,
                                      int& kitB, int& abyteA) {
  if (ISSUE) {
    abyteA += 32;
    na[U & 3] = lfrag(abase, abyteA);
    kitB += 32;
    nbB[U & 3] = phB[kitB];
  }
  acc[0] = mfma32(Rng[U & 15], bhi, acc[0]);
  acc[1] = mfma32(Rng[(U + 12) & 15], bhi, acc[1]);
  acc[2] = mfma32(Rng[(U + 8) & 15], bhi, acc[2]);
  acc[3] = mfma32(Rng[(U + 4) & 15], bhi, acc[3]);
  if (CONSUME) {
    Rng[(U + 1) & 15] = na[(U + 1) & 3];
    bhi = nbB[(U + 1) & 3];
  }
}

__global__ __launch_bounds__(512) void k_mconv(const unsigned short* __restrict__ IMPREV,
                                               const f16x8* __restrict__ PH,
                                               float* __restrict__ out) {
  const int tid = threadIdx.x;
  const int s = tid >> 6, lane = tid & 63;
  int w = blockIdx.x;
  {  // bijective XCD swizzle, nwg=250 (q=31, r=2)
    const int q = NWG_ / 8, r = NWG_ % 8;
    const int xcd = w & 7, o = w >> 3;
    w = (xcd < r ? xcd * (q + 1) : r * (q + 1) + (xcd - r) * q) + o;
  }
  const int Q0 = w << 8;                    // 256 outputs per block

  // A addressing: frag(q, step) at u = u0 + 16*step - 64*q (u0 for q=0,step=0)
  const int c = (lane & 1) ^ 1;             // parity copy selector (makes u0 even)
  const unsigned short* abase = IMPREV + (c ? ISTRIDE_ : 0);
  const int u0 = 255 + 2048 * s - (lane & 31) + 8 * (lane >> 5) - c;
  const int A0 = 2 * u0;                    // byte offset of frag(0, step 0)

  // Ring init (BUGFIX vs r16): slot k is pre-read (before its first install at end of
  // step k-1) iff k==0 or k>=4, always with the value u = u0 + 16*(k-16) [k=0: u0].
  // Slots 1..3 are provably never read pre-install -> zero.
  f16x8 Rng[16];
  Rng[0] = lfrag(abase, A0);
#pragma unroll
  for (int k = 1; k < 4; ++k) Rng[k] = (f16x8)((_Float16)0.f);
#pragma unroll
  for (int k = 4; k < 16; ++k) Rng[k] = lfrag(abase, A0 + 32 * k - 512);

  f32x16 acc[4];
#pragma unroll
  for (int q = 0; q < 4; ++q) acc[q] = (f32x16)(0.f);

  // B: lane holds sig[X + 8*(l>>5) + j + 32*grp][b], grp = (l>>4)&1, b = l&15
  const f16x8* phB = PH + 16 * (lane >> 5) + 64 * ((lane >> 4) & 1) + (lane & 15);
  const int kB0 = (Q0 + 2048 * s) << 1;
  f16x8 bhi = phB[kB0];
  f16x8 na[4], nbB[4];
  na[1] = lfrag(abase, A0 + 32);  nbB[1] = phB[kB0 + 32];   // step 1
  na[2] = lfrag(abase, A0 + 64);  nbB[2] = phB[kB0 + 64];   // step 2
  na[3] = lfrag(abase, A0 + 96);  nbB[3] = phB[kB0 + 96];   // step 3
  int abyteA = A0 + 96;
  int kitB = kB0 + 96;

  for (int ii = 0; ii < 7; ++ii) {          // steps 0..111
    cstep<0, true, true>(Rng, acc, bhi, na, nbB, phB, abase, kitB, abyteA);
    cstep<1, true, true>(Rng, acc, bhi, na, nbB, phB, abase, kitB, abyteA);
    cstep<2, true, true>(Rng, acc, bhi, na, nbB, phB, abase, kitB, abyteA);
    cstep<3, true, true>(Rng, acc, bhi, na, nbB, phB, abase, kitB, abyteA);
    cstep<4, true, true>(Rng, acc, bhi, na, nbB, phB, abase, kitB, abyteA);
    cstep<5, true, true>(Rng, acc, bhi, na, nbB, phB, abase, kitB, abyteA);
    cstep<6, true, true>(Rng, acc, bhi, na, nbB, phB, abase, kitB, abyteA);
    cstep<7, true, true>(Rng, acc, bhi, na, nbB, phB, abase, kitB, abyteA);
    cstep<8, true, true>(Rng, acc, bhi, na, nbB, phB, abase, kitB, abyteA);
    cstep<9, true, true>(Rng, acc, bhi, na, nbB, phB, abase, kitB, abyteA);
    cstep<10, true, true>(Rng, acc, bhi, na, nbB, phB, abase, kitB, abyteA);
    cstep<11, true, true>(Rng, acc, bhi, na, nbB, phB, abase, kitB, abyteA);
    cstep<12, true, true>(Rng, acc, bhi, na, nbB, phB, abase, kitB, abyteA);
    cstep<13, true, true>(Rng, acc, bhi, na, nbB, phB, abase, kitB, abyteA);
    cstep<14, true, true>(Rng, acc, bhi, na, nbB, phB, abase, kitB, abyteA);
    cstep<15, true, true>(Rng, acc, bhi, na, nbB, phB, abase, kitB, abyteA);
  }
  // tail: steps 112..127 (issue stops after step 123; consume after 126)
  cstep<0, true, true>(Rng, acc, bhi, na, nbB, phB, abase, kitB, abyteA);   // 112
  cstep<1, true, true>(Rng, acc, bhi, na, nbB, phB, abase, kitB, abyteA);   // 113
  cstep<2, true, true>(Rng, acc, bhi, na, nbB, phB, abase, kitB, abyteA);   // 114
  cstep<3, true, true>(Rng, acc, bhi, na, nbB, phB, abase, kitB, abyteA);   // 115
  cstep<4, true, true>(Rng, acc, bhi, na, nbB, phB, abase, kitB, abyteA);   // 116
  cstep<5, true, true>(Rng, acc, bhi, na, nbB, phB, abase, kitB, abyteA);   // 117
  cstep<6, true, true>(Rng, acc, bhi, na, nbB, phB, abase, kitB, abyteA);   // 118
  cstep<7, true, true>(Rng, acc, bhi, na, nbB, phB, abase, kitB, abyteA);   // 119
  cstep<8, true, true>(Rng, acc, bhi, na, nbB, phB, abase, kitB, abyteA);   // 120
  cstep<9, true, true>(Rng, acc, bhi, na, nbB, phB, abase, kitB, abyteA);   // 121
  cstep<10, true, true>(Rng, acc, bhi, na, nbB, phB, abase, kitB, abyteA);  // 122
  cstep<11, true, true>(Rng, acc, bhi, na, nbB, phB, abase, kitB, abyteA);  // 123
  cstep<12, false, true>(Rng, acc, bhi, na, nbB, phB, abase, kitB, abyteA); // 124
  cstep<13, false, true>(Rng, acc, bhi, na, nbB, phB, abase, kitB, abyteA); // 125
  cstep<14, false, true>(Rng, acc, bhi, na, nbB, phB, abase, kitB, abyteA); // 126
  cstep<15, false, false>(Rng, acc, bhi, na, nbB, phB, abase, kitB, abyteA);// 127

  // two-stage cross-wave (K-split) reduction, then coalesced f32x4 stores
  __shared__ f32x4 part[4][4][4][64];       // [kw][q][rg][lane]
  if (s < 4) {
#pragma unroll
    for (int q = 0; q < 4; ++q)
#pragma unroll
      for (int rg = 0; rg < 4; ++rg)
        part[s][q][rg][lane] =
            (f32x4){acc[q][4 * rg], acc[q][4 * rg + 1], acc[q][4 * rg + 2], acc[q][4 * rg + 3]};
  }
  __syncthreads();
  if (s >= 4) {
#pragma unroll
    for (int q = 0; q < 4; ++q)
#pragma unroll
      for (int rg = 0; rg < 4; ++rg)
        part[s - 4][q][rg][lane] +=
            (f32x4){acc[q][4 * rg], acc[q][4 * rg + 1], acc[q][4 * rg + 2], acc[q][4 * rg + 3]};
  }
  __syncthreads();
#pragma unroll
  for (int half = 0; half < 2; ++half) {
    const int it = tid + (half << 9);       // < 1024
    const int ln = it & 63, rg = (it >> 6) & 3, q = it >> 8;
    f32x4 v = part[0][q][rg][ln];
    v += part[1][q][rg][ln];
    v += part[2][q][rg][ln];
    v += part[3][q][rg][ln];
    const int b = ln & 15;
    const int pos = Q0 + 64 * q + 32 * ((ln >> 4) & 1) + 8 * rg + 4 * (ln >> 5);
    *(f32x4*)(out + (size_t)b * N_ + pos) = v;
  }
}

extern "C" void kernel_launch(void* const* d_in, const int* in_sizes, int n_in,
                              void* d_out, int out_size, void* d_ws, size_t ws_size,
                              hipStream_t stream) {
  const float* pitch = (const float*)d_in[0];
  const float* tamp  = (const float*)d_in[1];
  const float* harmo = (const float*)d_in[2];
  const float* nfilt = (const float*)d_in[3];
  const float* noise = (const float*)d_in[4];
  const float* rn    = (const float*)d_in[5];
  const float* dec   = (const float*)d_in[6];
  const float* wet   = (const float*)d_in[7];

  char* ws = (char*)d_ws;
  size_t off = 0;
  _Float16* PH = (_Float16*)(ws + off);     off += (size_t)KTOT2_ * 16 * 2;  // 2.57 MB
  _Float16* IMPREV = (_Float16*)(ws + off); off += (size_t)2 * ISTRIDE_ * 2; // 67 KB
  double* Pv = (double*)(ws + off);         off += (size_t)B_ * T_ * 8;
  double* Xv = (double*)(ws + off);         off += (size_t)B_ * T_ * 8;
  float* out = (float*)d_out;

  k_pre<<<dim3(146), dim3(512), 0, stream>>>(pitch, rn, dec, wet, Pv, Xv, IMPREV, PH);
  k_synth<<<dim3(B_ * T_ / 2), dim3(320), 0, stream>>>(pitch, tamp, harmo, nfilt, noise, Pv, Xv, PH);
  k_mconv<<<dim3(NWG_), dim3(512), 0, stream>>>((const unsigned short*)IMPREV, (const f16x8*)PH, out);
}

// Round 18
// 57.851 us; speedup vs baseline: 1.1021x; 1.1021x over previous
//
#include <hip/hip_runtime.h>

#define B_ 16
#define T_ 400
#define NH_ 100
#define NB_ 65
#define BLK_ 160
#define SR_ 16000
#define N_ 64000           // T_*BLK_
#define REV_ 16000
#define KPAD_ 16128        // front zero pad of signal
#define KTOT_ 80128        // KPAD_ + N_
#define M_ 16              // m-tiles per wave (256 outputs)
#define NWG_ 250           // 256 outputs per block
#define ISTRIDE_ 16768     // elems per IMPREV copy (valid span 16704)

typedef __attribute__((ext_vector_type(8))) _Float16 f16x8;
typedef __attribute__((ext_vector_type(2))) _Float16 f16x2;
typedef __attribute__((ext_vector_type(4))) float f32x4;
typedef __attribute__((ext_vector_type(4))) unsigned uint4v;
typedef uint4v __attribute__((aligned(4))) uint4v_a4;

static __device__ __forceinline__ float dot2f(f16x2 a, f16x2 b, float c) {
#if __has_builtin(__builtin_amdgcn_fdot2)
  return __builtin_amdgcn_fdot2(a, b, c, false);
#else
  return fmaf((float)a[0], (float)b[0], fmaf((float)a[1], (float)b[1], c));
#endif
}

// ---------------- K0: merged IMPREV build (66 blk) + PH front-pad zero (63) + fp64 prefix (16) ----------------
// IMPREV[c][u] = imp[16383 - u - c] (0 outside [0,REV_)), imp[0]=1.
__global__ __launch_bounds__(512) void k_pre(const float* __restrict__ pitch,
                                             const float* __restrict__ rn,
                                             const float* __restrict__ dec,
                                             const float* __restrict__ wet,
                                             double* __restrict__ Pv,
                                             double* __restrict__ Xv,
                                             _Float16* __restrict__ IMPREV,
                                             _Float16* __restrict__ PH) {
  const int blk = blockIdx.x, tid = threadIdx.x;
  if (blk < 66) {
    const int gid = blk * 512 + tid;
    if (gid < 2 * ISTRIDE_) {
      const int c = gid / ISTRIDE_, u = gid - c * ISTRIDE_;
      const int i = 16383 - u - c;
      float v = 0.f;
      if (i == 0) {
        v = 1.0f;
      } else if (i > 0 && i < REV_) {
        const float a = log1pf(expf(-dec[0]));
        const float sg = 1.f / (1.f + expf(-wet[0]));
        v = rn[i] * expf(-a * ((float)i / (float)SR_) * 500.0f) * sg;
      }
      IMPREV[gid] = (_Float16)v;
    }
    return;
  }
  if (blk < 129) {
    const int gid = (blk - 66) * 512 + tid;   // < 32256
    ((f32x4*)PH)[gid] = (f32x4){0.f, 0.f, 0.f, 0.f};
    return;
  }
  // ---- prefix branch ----
  __shared__ double s[512];
  const int b = blk - 129, t = tid;
  double x = 0.0;
  if (t < T_) x = (double)pitch[b * T_ + t] * (1.0 / (double)SR_);
  s[t] = x;
  __syncthreads();
  for (int off = 1; off < 512; off <<= 1) {
    double v = (t >= off) ? s[t - off] : 0.0;
    __syncthreads();
    s[t] += v;
    __syncthreads();
  }
  if (t < T_) {
    Xv[b * T_ + t] = x;
    Pv[b * T_ + t] = (s[t] - x) * 160.0;
  }
}

// ---------------- K2: dual-column harmonic synth + filtered noise -> packed fp16 (r8-identical) ----------------
__global__ __launch_bounds__(320) void k_synth(
    const float* __restrict__ pitch, const float* __restrict__ tamp,
    const float* __restrict__ harmo, const float* __restrict__ nfilt,
    const float* __restrict__ noise, const double* __restrict__ Pv,
    const double* __restrict__ Xv, _Float16* __restrict__ PH) {
  const int tid = threadIdx.x;
  const int g = (tid >= 160) ? 1 : 0;
  const int ltid = tid - (g << 7) - (g << 5);  // tid - 160*g
  const int bt = (blockIdx.x << 1) + g;
  const int b = bt / T_, t = bt - b * T_;
  __shared__ __align__(16) float amp[2][112];
  __shared__ __align__(16) float a_s[2][68];
  __shared__ __align__(16) float ir_s[2][68];
  __shared__ __align__(16) _Float16 C0[2][320];
  __shared__ __align__(16) _Float16 C1[2][320];
  __shared__ __align__(16) _Float16 imp_sw[2][128];
  __shared__ float red_s[2];

  const float pv = pitch[bt];
  int nv = (int)(8000.0f / pv);
  if (nv > NH_) nv = NH_;
  while (nv < NH_ && (float)(nv + 1) * pv < 8000.0f) ++nv;
  while (nv > 0 && (float)nv * pv >= 8000.0f) --nv;

  if (ltid < NB_) a_s[g][ltid] = nfilt[bt * NB_ + ltid];
  {
    const _Float16 nh = (_Float16)noise[bt * BLK_ + ltid];
    C0[g][160 + ltid] = nh;
    C1[g][159 + ltid] = nh;
    C0[g][ltid] = (_Float16)0.f;
    if (ltid < 159) C1[g][ltid] = (_Float16)0.f;
  }
  if (ltid < NH_) {
    const float ha = harmo[(b * NH_ + ltid) * T_ + t];
    const float aa = (pv * (float)(ltid + 1) < 8000.0f ? 1.0f : 0.0f) + 1e-4f;
    amp[g][ltid] = ha * aa;
  } else if (ltid < 112) {
    amp[g][ltid] = 0.f;
  }
  __syncthreads();  // B1

  float irv = 0.f;
  if (ltid < 65) {
    const float phi = (float)ltid * (1.0f / 128.0f);
    const float c1 = __builtin_amdgcn_cosf(phi);
    const float c2 = fmaf(2.f * c1, c1, -1.f);
    const float c3 = fmaf(2.f * c2, c1, -c1);
    const float c4 = fmaf(2.f * c2, c2, -1.f);
    const float tc = 2.f * c4;
    float x0 = 1.f, p0 = c4;
    float x1 = c1, p1 = c3;
    float x2 = c2, p2 = c2;
    float x3 = c3, p3 = c1;
    float a0 = 0.f, a1 = 0.f, a2 = 0.f, a3 = 0.f;
#pragma unroll
    for (int m = 0; m < 8; ++m) {
      const f32x4 aA = *(const f32x4*)&a_s[g][m << 3];
      const f32x4 aB = *(const f32x4*)&a_s[g][(m << 3) + 4];
      a0 = fmaf(aA[0], x0, a0); const float y0 = fmaf(tc, x0, -p0);
      a1 = fmaf(aA[1], x1, a1); const float y1 = fmaf(tc, x1, -p1);
      a2 = fmaf(aA[2], x2, a2); const float y2 = fmaf(tc, x2, -p2);
      a3 = fmaf(aA[3], x3, a3); const float y3 = fmaf(tc, x3, -p3);
      a0 = fmaf(aB[0], y0, a0); const float z0 = fmaf(tc, y0, -x0); p0 = y0; x0 = z0;
      a1 = fmaf(aB[1], y1, a1); const float z1 = fmaf(tc, y1, -x1); p1 = y1; x1 = z1;
      a2 = fmaf(aB[2], y2, a2); const float z2 = fmaf(tc, y2, -x2); p2 = y2; x2 = z2;
      a3 = fmaf(aB[3], y3, a3); const float z3 = fmaf(tc, y3, -x3); p3 = y3; x3 = z3;
    }
    const float accS = (a0 + a1) + (a2 + a3);
    irv = (2.f * accS - a_s[g][0] + ((ltid & 1) ? -a_s[g][64] : a_s[g][64])) * (1.0f / 128.0f);
    ir_s[g][ltid] = irv;
  } else if (ltid >= 128) {
    const int l = ltid - 128;
    float v = amp[g][l] + amp[g][l + 32] + amp[g][l + 64] + (l < 4 ? amp[g][l + 96] : 0.f);
    v += __shfl_xor(v, 16);
    v += __shfl_xor(v, 8);
    v += __shfl_xor(v, 4);
    v += __shfl_xor(v, 2);
    v += __shfl_xor(v, 1);
    if (l == 0) red_s[g] = v;
  }
  __syncthreads();  // B2

  if (ltid < 64) {
    const float w = 0.5f + 0.5f * __builtin_amdgcn_cosf((float)ltid * (1.0f / 128.0f));
    imp_sw[g][ltid ^ 1] = (_Float16)(w * irv);
  } else if (ltid >= 96 && ltid < 160) {
    const int u = ltid - 96;
    const float w = 0.5f - 0.5f * __builtin_amdgcn_cosf((float)u * (1.0f / 128.0f));
    imp_sw[g][64 + (u ^ 1)] = (_Float16)(w * ir_s[g][64 - u]);
  }
  const float scale = tamp[bt] / red_s[g];
  double th = Pv[bt] + (double)(ltid + 1) * Xv[bt];
  th -= floor(th);
  const float theta = (float)th;
  const float cT = __builtin_amdgcn_cosf(theta);
  const float sT = __builtin_amdgcn_sinf(theta);
  __syncthreads();  // B3

  float acc;
  {
    const float c2 = fmaf(cT, cT, -sT * sT);
    const float s2 = 2.f * cT * sT;
    const float s3 = fmaf(s2, cT, c2 * sT);
    const float s4 = 2.f * s2 * c2;
    const float c4 = fmaf(2.f * c2, c2, -1.f);
    const float tc = 2.f * c4;
    float x0 = sT, p0 = -s3;
    float x1 = s2, p1 = -s2;
    float x2 = s3, p2 = -sT;
    float x3 = s4, p3 = 0.f;
    float a0 = 0.f, a1 = 0.f, a2 = 0.f, a3 = 0.f;
    const int S = (nv + 7) >> 3;
    for (int m = 0; m < S; ++m) {
      const f32x4 aA = *(const f32x4*)&amp[g][m << 3];
      const f32x4 aB = *(const f32x4*)&amp[g][(m << 3) + 4];
      a0 = fmaf(aA[0], x0, a0); const float y0 = fmaf(tc, x0, -p0);
      a1 = fmaf(aA[1], x1, a1); const float y1 = fmaf(tc, x1, -p1);
      a2 = fmaf(aA[2], x2, a2); const float y2 = fmaf(tc, x2, -p2);
      a3 = fmaf(aA[3], x3, a3); const float y3 = fmaf(tc, x3, -p3);
      a0 = fmaf(aB[0], y0, a0); const float z0 = fmaf(tc, y0, -x0); p0 = y0; x0 = z0;
      a1 = fmaf(aB[1], y1, a1); const float z1 = fmaf(tc, y1, -x1); p1 = y1; x1 = z1;
      a2 = fmaf(aB[2], y2, a2); const float z2 = fmaf(tc, y2, -x2); p2 = y2; x2 = z2;
      a3 = fmaf(aB[3], y3, a3); const float z3 = fmaf(tc, y3, -x3); p3 = y3; x3 = z3;
    }
    acc = ((a0 + a1) + (a2 + a3)) * scale;
  }

  float nf = 0.f;
  {
    const f16x2* np0;
    int pe;
    if (ltid & 1) {
      np0 = (const f16x2*)C0[g];
      pe = (159 + ltid) >> 1;
    } else {
      np0 = (const f16x2*)C1[g];
      pe = (158 + ltid) >> 1;
    }
    const f16x8* ip = (const f16x8*)imp_sw[g];
#pragma unroll
    for (int k0 = 0; k0 < 8; ++k0) {
      const f16x8 i8 = ip[k0];
      const int kb = k0 << 2;
      nf = dot2f((f16x2){i8[0], i8[1]}, np0[pe - kb], nf);
      nf = dot2f((f16x2){i8[2], i8[3]}, np0[pe - kb - 1], nf);
      nf = dot2f((f16x2){i8[4], i8[5]}, np0[pe - kb - 2], nf);
      nf = dot2f((f16x2){i8[6], i8[7]}, np0[pe - kb - 3], nf);
    }
#pragma unroll
    for (int k0 = 0; k0 < 8; ++k0) {
      const f16x8 i8 = ip[8 + k0];
      const int kb = (k0 << 2) + 48;
      nf = dot2f((f16x2){i8[0], i8[1]}, np0[pe - kb], nf);
      nf = dot2f((f16x2){i8[2], i8[3]}, np0[pe - kb - 1], nf);
      nf = dot2f((f16x2){i8[4], i8[5]}, np0[pe - kb - 2], nf);
      nf = dot2f((f16x2){i8[6], i8[7]}, np0[pe - kb - 3], nf);
    }
  }

  const float v = acc + nf;
  const unsigned k = (unsigned)(KPAD_ + t * BLK_ + ltid);
  const unsigned off = ((k >> 3) << 7) + ((unsigned)b << 3) + (k & 7u);
  PH[off] = (_Float16)v;
}

// ---------------- K4: reverb Toeplitz MFMA GEMM — r11 geometry (M=16), depth-4 prefetch ----------------
static __device__ __forceinline__ f32x4 mfma_f16(f16x8 a, f16x8 b, f32x4 c) {
  return __builtin_amdgcn_mfma_f32_16x16x32_f16(a, b, c, 0, 0, 0);
}

static __device__ __forceinline__ f16x8 lfrag(const unsigned short* __restrict__ base, int byteoff) {
  union { uint4v u; f16x8 v; } x;
  x.u = *(const uint4v_a4*)((const char*)base + byteoff);  // single dwordx4, 4B-aligned
  return x.v;
}

template <int U, bool ISSUE, bool CONSUME>
__device__ __forceinline__ void conv_step(f16x8 (&Rh)[M_], f32x4 (&acc)[M_], f16x8 (&bhi2)[2],
                                          f16x8 (&nb)[4], f16x8 (&na0)[4], f16x8 (&na1)[4],
                                          const f16x8* __restrict__ ph,
                                          const unsigned short* __restrict__ abase,
                                          int& kit, int& abyte) {
  if (ISSUE) {  // loads for step U+4 into buf[U&3]
    kit += 64;               // +32 samples = +64 f16x8 units
    nb[U & 3] = ph[kit];
    abyte += 64;             // t -= 2  ->  A byte offset += 64
    na0[U & 3] = lfrag(abase, abyte);        // entry t
    na1[U & 3] = lfrag(abase, abyte - 32);   // entry t+1
  }
#pragma unroll
  for (int mm = 0; mm < M_; ++mm) {
    const int m = (mm + M_ - 2) & (M_ - 1);  // doomed ring slots read first
    const int sl = (m - 2 * U) & (M_ - 1);
    acc[m] = mfma_f16(Rh[sl], bhi2[U & 1], acc[m]);
  }
  if (CONSUME) {  // install data for step U+1 (issued at step U-3, buf[(U+1)&3])
    Rh[(M_ - 2 - 2 * U) & (M_ - 1)] = na0[(U + 1) & 3];
    Rh[(M_ - 1 - 2 * U) & (M_ - 1)] = na1[(U + 1) & 3];
    bhi2[(U + 1) & 1] = nb[(U + 1) & 3];
  }
}

__global__ __launch_bounds__(512) void k_mconv(const unsigned short* __restrict__ IMPREV,
                                               const f16x8* __restrict__ PH,
                                               float* __restrict__ out) {
  const int tid = threadIdx.x;
  const int s = tid >> 6, lane = tid & 63;
  int w = blockIdx.x;
  {  // bijective XCD swizzle, nwg=250 (q=31, r=2)
    const int q = NWG_ / 8, r = NWG_ % 8;
    const int xcd = w & 7, o = w >> 3;
    w = (xcd < r ? xcd * (q + 1) : r * (q + 1) + (xcd - r) * q) + o;
  }
  const int Q0 = w << 8;                    // 256 outputs per block
  const int T0 = 1022 - 128 * s;            // frag-table t at step 0, m=0 (r4-verified)

  // per-lane compact-A addressing (r11-verified)
  const int pat = (lane & 15) - ((lane >> 4) << 3);
  const int o0 = 16223 - 16 * T0 - pat;
  const int par = o0 & 1;
  const unsigned short* abase = IMPREV + (par ? ISTRIDE_ : 0);
  int abyte = 2 * (384 + o0 - par);         // byte offset of entry T0

  f16x8 Rh[M_];
#pragma unroll
  for (int m = 0; m < M_; ++m) Rh[m] = lfrag(abase, abyte - 32 * m);  // entries T0..T0+15
  f32x4 acc[M_];
#pragma unroll
  for (int m = 0; m < M_; ++m) acc[m] = (f32x4){0.f, 0.f, 0.f, 0.f};

  const f16x8* ph = PH + ((lane >> 4) << 4) + (lane & 15);
  int kit = (Q0 + 2048 * s) << 1;           // unit index (r4-verified)
  f16x8 bhi2[2], nb[4], na0[4], na1[4];
  bhi2[0] = ph[kit];
  // prologue: issue steps 1,2,3 into bufs 1,2,3
  kit += 64; nb[1] = ph[kit]; abyte += 64; na0[1] = lfrag(abase, abyte); na1[1] = lfrag(abase, abyte - 32);
  kit += 64; nb[2] = ph[kit]; abyte += 64; na0[2] = lfrag(abase, abyte); na1[2] = lfrag(abase, abyte - 32);
  kit += 64; nb[3] = ph[kit]; abyte += 64; na0[3] = lfrag(abase, abyte); na1[3] = lfrag(abase, abyte - 32);

  for (int ii = 0; ii < 7; ++ii) {          // steps 0..55
    conv_step<0, true, true>(Rh, acc, bhi2, nb, na0, na1, ph, abase, kit, abyte);
    conv_step<1, true, true>(Rh, acc, bhi2, nb, na0, na1, ph, abase, kit, abyte);
    conv_step<2, true, true>(Rh, acc, bhi2, nb, na0, na1, ph, abase, kit, abyte);
    conv_step<3, true, true>(Rh, acc, bhi2, nb, na0, na1, ph, abase, kit, abyte);
    conv_step<4, true, true>(Rh, acc, bhi2, nb, na0, na1, ph, abase, kit, abyte);
    conv_step<5, true, true>(Rh, acc, bhi2, nb, na0, na1, ph, abase, kit, abyte);
    conv_step<6, true, true>(Rh, acc, bhi2, nb, na0, na1, ph, abase, kit, abyte);
    conv_step<7, true, true>(Rh, acc, bhi2, nb, na0, na1, ph, abase, kit, abyte);
  }
  // tail: steps 56..63
  conv_step<0, true, true>(Rh, acc, bhi2, nb, na0, na1, ph, abase, kit, abyte);   // 56 (issues 60)
  conv_step<1, true, true>(Rh, acc, bhi2, nb, na0, na1, ph, abase, kit, abyte);   // 57 (issues 61)
  conv_step<2, true, true>(Rh, acc, bhi2, nb, na0, na1, ph, abase, kit, abyte);   // 58 (issues 62)
  conv_step<3, true, true>(Rh, acc, bhi2, nb, na0, na1, ph, abase, kit, abyte);   // 59 (issues 63)
  conv_step<4, false, true>(Rh, acc, bhi2, nb, na0, na1, ph, abase, kit, abyte);  // 60
  conv_step<5, false, true>(Rh, acc, bhi2, nb, na0, na1, ph, abase, kit, abyte);  // 61
  conv_step<6, false, true>(Rh, acc, bhi2, nb, na0, na1, ph, abase, kit, abyte);  // 62
  conv_step<7, false, false>(Rh, acc, bhi2, nb, na0, na1, ph, abase, kit, abyte); // 63

  // two-stage cross-wave (K-split) reduction in LDS, then coalesced stores (r4-verified)
  __shared__ f32x4 part[4][M_][64];
  if (s < 4) {
#pragma unroll
    for (int m = 0; m < M_; ++m) part[s][m][lane] = acc[m];
  }
  __syncthreads();
  if (s >= 4) {
#pragma unroll
    for (int m = 0; m < M_; ++m) part[s - 4][m][lane] += acc[m];
  }
  __syncthreads();
#pragma unroll
  for (int half = 0; half < 2; ++half) {
    const int it = tid + (half << 9);
    const int m = it >> 6, ln = it & 63;
    f32x4 v = part[0][m][ln];
    v += part[1][m][ln];
    v += part[2][m][ln];
    v += part[3][m][ln];
    const int b = ln & 15, gq = ln >> 4;
    *(f32x4*)(out + (size_t)b * N_ + Q0 + (m << 4) + (gq << 2)) = v;
  }
}

extern "C" void kernel_launch(void* const* d_in, const int* in_sizes, int n_in,
                              void* d_out, int out_size, void* d_ws, size_t ws_size,
                              hipStream_t stream) {
  const float* pitch = (const float*)d_in[0];
  const float* tamp  = (const float*)d_in[1];
  const float* harmo = (const float*)d_in[2];
  const float* nfilt = (const float*)d_in[3];
  const float* noise = (const float*)d_in[4];
  const float* rn    = (const float*)d_in[5];
  const float* dec   = (const float*)d_in[6];
  const float* wet   = (const float*)d_in[7];

  char* ws = (char*)d_ws;
  size_t off = 0;
  _Float16* PH = (_Float16*)(ws + off);     off += (size_t)KTOT_ * 16 * 2;   // 2.56 MB
  _Float16* IMPREV = (_Float16*)(ws + off); off += (size_t)2 * ISTRIDE_ * 2; // 67 KB
  double* Pv = (double*)(ws + off);         off += (size_t)B_ * T_ * 8;
  double* Xv = (double*)(ws + off);         off += (size_t)B_ * T_ * 8;
  float* out = (float*)d_out;

  k_pre<<<dim3(145), dim3(512), 0, stream>>>(pitch, rn, dec, wet, Pv, Xv, IMPREV, PH);
  k_synth<<<dim3(B_ * T_ / 2), dim3(320), 0, stream>>>(pitch, tamp, harmo, nfilt, noise, Pv, Xv, PH);
  k_mconv<<<dim3(NWG_), dim3(512), 0, stream>>>((const unsigned short*)IMPREV, (const f16x8*)PH, out);
}